// Round 10
// baseline (669.169 us; speedup 1.0000x reference)
//
#include <hip/hip_runtime.h>
#include <hip/hip_bf16.h>
#include <stdint.h>

#define DEV __device__ __forceinline__

typedef short s16x8 __attribute__((ext_vector_type(8)));
typedef float f32x4 __attribute__((ext_vector_type(4)));
typedef int i32x4 __attribute__((ext_vector_type(4)));

// async 16B global->LDS. LDS side is wave-uniform base + lane*16 (HW rule).
DEV void async_load16(const void* g, void* l) {
  __builtin_amdgcn_global_load_lds((void __attribute__((address_space(1)))*)(g),
                                   (void __attribute__((address_space(3)))*)(l),
                                   16, 0, 0);
}

DEV unsigned pack_bf16x2(float a, float b) {
  __hip_bfloat162 h = __float22bfloat162_rn(make_float2(a, b));
  union { __hip_bfloat162 h2; unsigned u; } cv;
  cv.h2 = h;
  return cv.u;
}

// ---------------- cast x fp32 -> bf16 ----------------
__global__ __launch_bounds__(256) void cast_x_kernel(const float* __restrict__ in,
                                                     __hip_bfloat16* __restrict__ out, int n4) {
  int i = blockIdx.x * 256 + threadIdx.x;
  if (i >= n4) return;
  float4 v = ((const float4*)in)[i];
  alignas(8) __hip_bfloat16 t[4] = {__float2bfloat16(v.x), __float2bfloat16(v.y),
                                    __float2bfloat16(v.z), __float2bfloat16(v.w)};
  *(uint2*)(out + (size_t)i * 4) = *(const uint2*)t;
}

// ------- transpose-cast: dst[b][c][r] = src[b][r][c] * scale  (bf16 out) -------
__global__ __launch_bounds__(256) void transpose_cast_kernel(const float* __restrict__ src,
                                                             __hip_bfloat16* __restrict__ dst,
                                                             int R, int C, float scale) {
  __shared__ float tile[64][65];
  const int r0 = blockIdx.x * 64, c0 = blockIdx.y * 64, bt = blockIdx.z;
  const int tc = threadIdx.x & 63, tr = threadIdx.x >> 6;
  const float* sp = src + (size_t)bt * R * C;
#pragma unroll
  for (int rr = 0; rr < 64; rr += 4)
    tile[tr + rr][tc] = sp[(size_t)(r0 + tr + rr) * C + c0 + tc];
  __syncthreads();
  __hip_bfloat16* dp = dst + (size_t)bt * R * C;
#pragma unroll
  for (int rr = 0; rr < 64; rr += 4) {
    int cc = tr + rr;
    dp[(size_t)(c0 + cc) * R + r0 + tc] = __float2bfloat16(tile[tc][cc] * scale);
  }
}

// ------- fused Wq/Wk/Wv transpose-cast (R=1024, C=64, 16 heads each) -------
__global__ __launch_bounds__(256) void qkv_transpose_kernel(const float* __restrict__ Wq,
                                                            const float* __restrict__ Wk,
                                                            const float* __restrict__ Wv,
                                                            __hip_bfloat16* __restrict__ dst,
                                                            float qscale) {
  __shared__ float tile[64][65];
  const int z = blockIdx.z, which = z >> 4, bt = z & 15;
  const int r0 = blockIdx.x * 64;
  const int tc = threadIdx.x & 63, tr = threadIdx.x >> 6;
  const float* src = (which == 0) ? Wq : (which == 1) ? Wk : Wv;
  const float scale = (which == 0) ? qscale : 1.0f;
  const float* sp = src + (size_t)bt * 1024 * 64;
#pragma unroll
  for (int rr = 0; rr < 64; rr += 4)
    tile[tr + rr][tc] = sp[(size_t)(r0 + tr + rr) * 64 + tc];
  __syncthreads();
  __hip_bfloat16* dp = dst + (size_t)z * 1024 * 64;
#pragma unroll
  for (int rr = 0; rr < 64; rr += 4) {
    int cc = tr + rr;
    dp[(size_t)(cc)*1024 + r0 + tc] = __float2bfloat16(tile[tc][cc] * scale);
  }
}

// ---------------- 128x128 bf16 MFMA GEMM, BK=64, m97 structure (R15) ----------------
// C[M,N] = A[M,K] * Bt[N,K]^T.
// MODE 0 (fused QKV, N=3072): cols <1024 -> Q, <2048 -> K, >=2048 -> Vt packed-T.
// MODE 2: fp32 out0 = acc + bias[col] + resid[row*1024+col]
// R9 lesson: per-phase wave-gated compute serializes MFMAs across barriers — never
// gate compute on wave id. Reverted to the proven 2-barrier loop (all 4 waves
// compute concurrently). R15: BK 32->64 — the loop's structural tax is the
// vmcnt(0) drain at the second barrier; 16 K-iters instead of 32 halves the
// number of drains for the same staged bytes (32 MFMA + 16 ds_read per drain).
// LDS 32KB single-buffered; VGPR ~108 -> still 4 waves/SIMD.
// T1 bijective XCD swizzle kept (R7: small positive).
template <int MODE>
__global__ __launch_bounds__(256) void gemm128(const __hip_bfloat16* __restrict__ A,
                                               const __hip_bfloat16* __restrict__ Bt,
                                               void* __restrict__ out0,
                                               void* __restrict__ out1,
                                               void* __restrict__ out2,
                                               const float* __restrict__ bias,
                                               const float* __restrict__ resid,
                                               int M, int N, int K) {
  __shared__ __hip_bfloat16 As[128 * 64];
  __shared__ __hip_bfloat16 Bs[128 * 64];
  const int tid = threadIdx.x;
  const int lane = tid & 63, w = tid >> 6;
  const int lr = lane & 15, lq = lane >> 4;
  const int wm = w >> 1, wn = w & 1;
  const int nlin = blockIdx.x + gridDim.x * blockIdx.y;
  const int xcd = nlin & 7, slot = nlin >> 3;
  const int bx = slot >> 3;
  const int by = xcd * 8 + (slot & 7);
  const int m0 = by * 128, n0 = bx * 128;

  const f32x4 fz = {0.f, 0.f, 0.f, 0.f};
  f32x4 acc[4][4];
#pragma unroll
  for (int i = 0; i < 4; i++)
#pragma unroll
    for (int j = 0; j < 4; j++) acc[i][j] = fz;

  const int kiters = K >> 6;
  for (int kt = 0; kt < kiters; kt++) {
    __syncthreads();
    // stage: 128 rows x 128B per matrix = 1024 chunks; 4 rounds x 256 threads.
    // row-major LDS [row][8 chunks]; dest linear in c (wave-uniform + lane*16).
#pragma unroll
    for (int r = 0; r < 4; r++) {
      const int c = r * 256 + tid;
      const int row = c >> 3, ck = c & 7;
      async_load16((const short*)A + (size_t)(m0 + row) * K + kt * 64 + ck * 8,
                   (char*)As + (r * 256 + (tid & 0xC0)) * 16);
      async_load16((const short*)Bt + (size_t)(n0 + row) * K + kt * 64 + ck * 8,
                   (char*)Bs + (r * 256 + (tid & 0xC0)) * 16);
    }
    __syncthreads();
    const short* Ap = (const short*)As;
    const short* Bp = (const short*)Bs;
    s16x8 av[4][2], bv[4][2];
#pragma unroll
    for (int i = 0; i < 4; i++)
#pragma unroll
      for (int ks = 0; ks < 2; ks++)
        av[i][ks] = *(const s16x8*)(Ap + (wm * 64 + i * 16 + lr) * 64 + ks * 32 + lq * 8);
#pragma unroll
    for (int j = 0; j < 4; j++)
#pragma unroll
      for (int ks = 0; ks < 2; ks++)
        bv[j][ks] = *(const s16x8*)(Bp + (wn * 64 + j * 16 + lr) * 64 + ks * 32 + lq * 8);
#pragma unroll
    for (int ks = 0; ks < 2; ks++)
#pragma unroll
      for (int i = 0; i < 4; i++)
#pragma unroll
        for (int j = 0; j < 4; j++)
          acc[i][j] =
              __builtin_amdgcn_mfma_f32_16x16x32_bf16(av[i][ks], bv[j][ks], acc[i][j], 0, 0, 0);
  }

  if constexpr (MODE == 0) {
    if (n0 < 2048) {
      __hip_bfloat16* dst01 = (__hip_bfloat16*)((n0 < 1024) ? out0 : out1);
#pragma unroll
      for (int i = 0; i < 4; i++)
#pragma unroll
        for (int j = 0; j < 4; j++)
#pragma unroll
          for (int r = 0; r < 4; r++) {
            const int row = m0 + wm * 64 + i * 16 + lq * 4 + r;
            const int col = n0 + wn * 64 + j * 16 + lr;
            const int bb = row >> 11, s = row & 2047;
            const int colq = col & 1023;
            dst01[((((size_t)bb * 16 + (colq >> 6)) * 2048 + s) << 6) + (col & 63)] =
                __float2bfloat16(acc[i][j][r]);
          }
    } else {
      // V block: packed-transpose store to Vt[b][dhg][s] (4 consecutive s per lane)
#pragma unroll
      for (int i = 0; i < 4; i++)
#pragma unroll
        for (int j = 0; j < 4; j++) {
          const int row0 = m0 + wm * 64 + i * 16 + lq * 4;
          const int col = (n0 - 2048) + wn * 64 + j * 16 + lr;  // dh-global 0..1023
          const int bb = row0 >> 11, s0 = row0 & 2047;
          alignas(8) __hip_bfloat16 t4[4] = {
              __float2bfloat16(acc[i][j][0]), __float2bfloat16(acc[i][j][1]),
              __float2bfloat16(acc[i][j][2]), __float2bfloat16(acc[i][j][3])};
          *(uint2*)((__hip_bfloat16*)out2 + (size_t)bb * 2097152 + (size_t)col * 2048 + s0) =
              *(const uint2*)t4;
        }
    }
  } else {
#pragma unroll
    for (int i = 0; i < 4; i++)
#pragma unroll
      for (int j = 0; j < 4; j++)
#pragma unroll
        for (int r = 0; r < 4; r++) {
          const int row = m0 + wm * 64 + i * 16 + lq * 4 + r;
          const int col = n0 + wn * 64 + j * 16 + lr;
          const size_t idx = (size_t)row * 1024 + col;
          ((float*)out0)[idx] = acc[i][j][r] + bias[col] + resid[idx];
        }
  }
}

// ------------- streaming-softmax attention: 4-wave blocks, SINGLE-BUFFER (R15) -------------
// Q [B,H,S,64] pre-scaled by 0.125*log2(e) -> log2-domain scores, exp2 softmax.
// K [B,H,S,64], Vt [B,H,64,S] -> concat out [B,S,1024].
// R15: every flash result says TLP dominates (R3 win, R4/R5 losses, R1 dbuf
// neutral). dbuf's only cost is LDS: 32KB capped residency at 4 blocks/CU
// (measured ~2.8). Single 16KB staging buffer + 20.5KB epilogue-aliased smem ->
// 7 blocks/CU (launch_bounds(256,7); VGPR 52 << 73 cap). The now-exposed
// per-tile stage latency hides under ~2x more co-resident blocks.
// R9: 4 waves; wave pair (w>>1) owns q-tile pair; (w&1) picks the 32-kv half.
// R8: softmax row-sum on the MFMA pipe (ones-MFMA), no cross-lane reduction.
// R5 lesson: LDS staging IS the coalescer — keep it.
// CRITICAL (R6): register arrays never runtime-indexed (scratch demotion).
// Grid x=hb: XCD = blockid%8 = hb%8 -> all 32 qt of one (b,h) share K/V in one L2.
__global__ __launch_bounds__(256, 7) void flash_kernel(const __hip_bfloat16* __restrict__ Qg,
                                                       const __hip_bfloat16* __restrict__ Kg,
                                                       const __hip_bfloat16* __restrict__ Vtg,
                                                       __hip_bfloat16* __restrict__ Og) {
  // [0:8192) K   [8192:16384) V   — epilogue xch (20480B) aliases everything
  // (safe: last compute's LDS reads are fenced by the loop-end __syncthreads).
  __shared__ alignas(16) char smem[20480];
  float* xch = (float*)smem;  // slot stride 1280 f32: 1024 o + 256 ol
  const int tid = threadIdx.x;
  const int lane = tid & 63, w = tid >> 6;
  const int lr = lane & 15, lq = lane >> 4;
  const int qp = w >> 1;   // q-tile pair: global tiles {qp*2, qp*2+1}
  const int kvh = w & 1;   // which 32-kv half of the staged 64-kv tile
  const int hb = blockIdx.x, qt = blockIdx.y;
  const int h = hb >> 2, b = hb & 3;
  const size_t bh = (size_t)b * 16 + h;
  const short* Qbase = (const short*)Qg + (bh * 2048 + (size_t)qt * 64) * 64;
  const short* Kbh = (const short*)Kg + bh * 2048 * 64;
  const short* Vbh = (const short*)Vtg + bh * 64 * 2048;

  // tile-row->kv permutation pieces (in-lane P trick); gk == g(kvrow) == lr&7
  const int rbase = (lr >> 2) * 8 + (lr & 3);
  const int gk = lr & 7;

  // Q as B-operand fragments: this wave's 2 q-tiles (global tiles qp*2+ntl)
  s16x8 qb[2][2];
#pragma unroll
  for (int ntl = 0; ntl < 2; ntl++)
#pragma unroll
    for (int ks = 0; ks < 2; ks++)
      qb[ntl][ks] =
          *(const s16x8*)(Qbase + ((qp * 2 + ntl) * 16 + lr) * 64 + ks * 32 + lq * 8);

  // all-ones bf16 B-fragment for the row-sum MFMA
  s16x8 vones;
#pragma unroll
  for (int e = 0; e < 8; e++) vones[e] = (short)0x3F80;

  const f32x4 fz = {0.f, 0.f, 0.f, 0.f};
  f32x4 o[2][4];  // [local q-tile][dh n-tile] -- partial over this wave's kv half
  f32x4 ol[2];    // row-sum accumulator; row q = tile*16 + lq*4 + r
#pragma unroll
  for (int i = 0; i < 2; i++) {
    ol[i] = fz;
#pragma unroll
    for (int j = 0; j < 4; j++) o[i][j] = fz;
  }

  // stage K/V tile kb (4 async 16B loads / thread = 16KB / block)
  auto stage = [&](int kb) {
    char* Kl = smem;
    char* Vl = smem + 8192;
    const short* Ksrc = Kbh + kb * 64 * 64;
#pragma unroll
    for (int r = 0; r < 2; r++) {  // K tile: 64 rows x 128B, chunk xor g(row)
      int c = r * 256 + tid;
      int row = c >> 3, ck = c & 7;
      int g = (row & 3) | (((row >> 3) & 1) << 2);
      async_load16(Ksrc + row * 64 + (ck ^ g) * 8, Kl + (r * 256 + (tid & 0xC0)) * 16);
    }
#pragma unroll
    for (int r = 0; r < 2; r++) {  // Vt tile: 64 rows x 128B, chunk xor (row&7)
      int c = r * 256 + tid;
      int row = c >> 3, ck = c & 7;
      async_load16(Vbh + (size_t)row * 2048 + kb * 64 + ((ck ^ (row & 7))) * 8,
                   Vl + (r * 256 + (tid & 0xC0)) * 16);
    }
  };

  for (int kb = 0; kb < 32; kb++) {  // 64-kv tiles
    stage(kb);
    __syncthreads();  // vmcnt(0) drain + publish

    const short* Kp = (const short*)smem;
    const short* Vp = (const short*)(smem + 8192);

    // this wave's 32-kv half; S^T = K*Q^T, P built in-lane
    union { i32x4 i; s16x8 s; } pa[2];
#pragma unroll
    for (int mt = 0; mt < 2; mt++) {
      const int kvrow = kvh * 32 + mt * 4 + rbase;
      s16x8 kf0 = *(const s16x8*)(Kp + kvrow * 64 + (((0 * 4 + lq) ^ gk)) * 8);
      s16x8 kf1 = *(const s16x8*)(Kp + kvrow * 64 + (((1 * 4 + lq) ^ gk)) * 8);
#pragma unroll
      for (int ntl = 0; ntl < 2; ntl++) {
        f32x4 st = fz;
        st = __builtin_amdgcn_mfma_f32_16x16x32_bf16(kf0, qb[ntl][0], st, 0, 0, 0);
        st = __builtin_amdgcn_mfma_f32_16x16x32_bf16(kf1, qb[ntl][1], st, 0, 0, 0);
        float e0 = __builtin_amdgcn_exp2f(st[0]);
        float e1 = __builtin_amdgcn_exp2f(st[1]);
        float e2 = __builtin_amdgcn_exp2f(st[2]);
        float e3 = __builtin_amdgcn_exp2f(st[3]);
        pa[ntl].i[mt * 2 + 0] = (int)pack_bf16x2(e0, e1);
        pa[ntl].i[mt * 2 + 1] = (int)pack_bf16x2(e2, e3);
      }
    }
    __builtin_amdgcn_s_setprio(1);
#pragma unroll
    for (int ntl = 0; ntl < 2; ntl++)  // softmax row-sum on the MFMA pipe
      ol[ntl] = __builtin_amdgcn_mfma_f32_16x16x32_bf16(pa[ntl].s, vones, ol[ntl], 0, 0, 0);
#pragma unroll
    for (int ndh = 0; ndh < 4; ndh++) {
      int vrow = ndh * 16 + lr;
      s16x8 vb = *(const s16x8*)(Vp + vrow * 64 + (((kvh * 4 + lq) ^ (vrow & 7))) * 8);
#pragma unroll
      for (int ntl = 0; ntl < 2; ntl++)
        o[ntl][ndh] =
            __builtin_amdgcn_mfma_f32_16x16x32_bf16(pa[ntl].s, vb, o[ntl][ndh], 0, 0, 0);
    }
    __builtin_amdgcn_s_setprio(0);

    __syncthreads();  // all reads done before next stage overwrites
  }

  // ---- lane-linear exchange between kv-half partner waves (w <-> w^1) ----
  // wave w keeps local tile (w&1) [global tile w], ships local tile (w&1)^1.
  // ALL indices into o[]/ol[] are compile-time constants inside each branch.
  float* slot = xch + w * 1280;
  if (kvh == 0) {
#pragma unroll
    for (int ndh = 0; ndh < 4; ndh++)
      *(f32x4*)(slot + ndh * 256 + lane * 4) = o[1][ndh];
    *(f32x4*)(slot + 1024 + lane * 4) = ol[1];
  } else {
#pragma unroll
    for (int ndh = 0; ndh < 4; ndh++)
      *(f32x4*)(slot + ndh * 256 + lane * 4) = o[0][ndh];
    *(f32x4*)(slot + 1024 + lane * 4) = ol[0];
  }
  __syncthreads();
  const float* ps = xch + (w ^ 1) * 1280;
  if (kvh == 0) {
#pragma unroll
    for (int ndh = 0; ndh < 4; ndh++)
      o[0][ndh] += *(const f32x4*)(ps + ndh * 256 + lane * 4);
    f32x4 lt = ol[0] + *(const f32x4*)(ps + 1024 + lane * 4);
#pragma unroll
    for (int r = 0; r < 4; r++) {
      float inv = __builtin_amdgcn_rcpf(lt[r]);
      int rowg = qt * 64 + w * 16 + lq * 4 + r;
#pragma unroll
      for (int ndh = 0; ndh < 4; ndh++)
        Og[((size_t)b * 2048 + rowg) * 1024 + h * 64 + ndh * 16 + lr] =
            __float2bfloat16(o[0][ndh][r] * inv);
    }
  } else {
#pragma unroll
    for (int ndh = 0; ndh < 4; ndh++)
      o[1][ndh] += *(const f32x4*)(ps + ndh * 256 + lane * 4);
    f32x4 lt = ol[1] + *(const f32x4*)(ps + 1024 + lane * 4);
#pragma unroll
    for (int r = 0; r < 4; r++) {
      float inv = __builtin_amdgcn_rcpf(lt[r]);
      int rowg = qt * 64 + w * 16 + lq * 4 + r;
#pragma unroll
      for (int ndh = 0; ndh < 4; ndh++)
        Og[((size_t)b * 2048 + rowg) * 1024 + h * 64 + ndh * 16 + lr] =
            __float2bfloat16(o[1][ndh][r] * inv);
    }
  }
}

// ---------------- LayerNorm over last dim (1024) ----------------
__global__ __launch_bounds__(256) void ln_kernel(const float* __restrict__ tmp,
                                                 const float* __restrict__ gamma,
                                                 const float* __restrict__ beta,
                                                 float* __restrict__ out) {
  const int row = blockIdx.x, tid = threadIdx.x;
  const int lane = tid & 63, w = tid >> 6;
  const float* rp = tmp + (size_t)row * 1024;
  float4 v = ((const float4*)rp)[tid];
  float s = v.x + v.y + v.z + v.w;
  float ss = v.x * v.x + v.y * v.y + v.z * v.z + v.w * v.w;
#pragma unroll
  for (int off = 32; off >= 1; off >>= 1) {
    s += __shfl_xor(s, off);
    ss += __shfl_xor(ss, off);
  }
  __shared__ float red[8];
  if (lane == 0) {
    red[w] = s;
    red[4 + w] = ss;
  }
  __syncthreads();
  s = red[0] + red[1] + red[2] + red[3];
  ss = red[4] + red[5] + red[6] + red[7];
  const float mu = s * (1.0f / 1024.0f);
  const float var = ss * (1.0f / 1024.0f) - mu * mu;
  const float rstd = rsqrtf(var + 1e-5f);
  float4 g = ((const float4*)gamma)[tid];
  float4 be = ((const float4*)beta)[tid];
  float4 ov;
  ov.x = (v.x - mu) * rstd * g.x + be.x;
  ov.y = (v.y - mu) * rstd * g.y + be.y;
  ov.z = (v.z - mu) * rstd * g.z + be.z;
  ov.w = (v.w - mu) * rstd * g.w + be.w;
  ((float4*)(out + (size_t)row * 1024))[tid] = ov;
}

extern "C" void kernel_launch(void* const* d_in, const int* in_sizes, int n_in,
                              void* d_out, int out_size, void* d_ws, size_t ws_size,
                              hipStream_t stream) {
  (void)in_sizes; (void)n_in; (void)out_size; (void)ws_size;
  const float* x = (const float*)d_in[0];
  const float* Wq = (const float*)d_in[1];
  const float* Wk = (const float*)d_in[2];
  const float* Wv = (const float*)d_in[3];
  const float* Wo = (const float*)d_in[4];
  const float* bo = (const float*)d_in[5];
  const float* gamma = (const float*)d_in[6];
  const float* beta = (const float*)d_in[7];
  float* out = (float*)d_out;
  char* ws = (char*)d_ws;

  // workspace layout (bytes)
  __hip_bfloat16* xb = (__hip_bfloat16*)(ws + 0);          // 16 MB  [8192][1024]
  __hip_bfloat16* wqkvT = (__hip_bfloat16*)(ws + 16777216);// 6 MB   [3072][1024] (Wq x 0.125*log2e)
  __hip_bfloat16* woT = (__hip_bfloat16*)(ws + 23068672);  // 2 MB
  __hip_bfloat16* Q = (__hip_bfloat16*)(ws + 25165824);    // 16 MB [B,H,S,64]
  __hip_bfloat16* Kt = (__hip_bfloat16*)(ws + 41943040);   // 16 MB [B,H,S,64]
  __hip_bfloat16* Vt = (__hip_bfloat16*)(ws + 58720256);   // 16 MB [B,H,64,S]
  __hip_bfloat16* cc = (__hip_bfloat16*)(ws + 75497472);   // 16 MB [B,S,1024]
  float* tmp = (float*)(ws + 25165824);  // 32 MB fp32, aliases dead Q+Kt (stream-ordered)

  cast_x_kernel<<<8192, 256, 0, stream>>>(x, xb, 2097152);
  // Q scale folds 1/sqrt(64) and log2(e) so flash can use raw v_exp_f32 (exp2)
  qkv_transpose_kernel<<<dim3(16, 1, 48), 256, 0, stream>>>(Wq, Wk, Wv, wqkvT,
                                                            0.125f * 1.44269504088896f);
  transpose_cast_kernel<<<dim3(16, 16, 1), 256, 0, stream>>>(Wo, woT, 1024, 1024, 1.0f);

  // fused QKV projection: Bt = [wqT ; wkT ; wvT] (3072 rows, contiguous)
  gemm128<0><<<dim3(24, 64), 256, 0, stream>>>(xb, wqkvT, Q, Kt, Vt, nullptr, nullptr,
                                               8192, 3072, 1024);

  flash_kernel<<<dim3(64, 32), 256, 0, stream>>>(Q, Kt, Vt, cc);

  gemm128<2><<<dim3(8, 64), 256, 0, stream>>>(cc, woT, tmp, nullptr, nullptr, bo, x,
                                              8192, 1024, 1024);
  ln_kernel<<<8192, 256, 0, stream>>>(tmp, gamma, beta, out);
}

// Round 11
// 296.242 us; speedup vs baseline: 2.2589x; 2.2589x over previous
//
#include <hip/hip_runtime.h>
#include <hip/hip_bf16.h>
#include <stdint.h>

#define DEV __device__ __forceinline__

typedef short s16x8 __attribute__((ext_vector_type(8)));
typedef float f32x4 __attribute__((ext_vector_type(4)));
typedef int i32x4 __attribute__((ext_vector_type(4)));

// async 16B global->LDS. LDS side is wave-uniform base + lane*16 (HW rule).
DEV void async_load16(const void* g, void* l) {
  __builtin_amdgcn_global_load_lds((void __attribute__((address_space(1)))*)(g),
                                   (void __attribute__((address_space(3)))*)(l),
                                   16, 0, 0);
}

DEV unsigned pack_bf16x2(float a, float b) {
  __hip_bfloat162 h = __float22bfloat162_rn(make_float2(a, b));
  union { __hip_bfloat162 h2; unsigned u; } cv;
  cv.h2 = h;
  return cv.u;
}

// ---------------- cast x fp32 -> bf16 ----------------
__global__ __launch_bounds__(256) void cast_x_kernel(const float* __restrict__ in,
                                                     __hip_bfloat16* __restrict__ out, int n4) {
  int i = blockIdx.x * 256 + threadIdx.x;
  if (i >= n4) return;
  float4 v = ((const float4*)in)[i];
  alignas(8) __hip_bfloat16 t[4] = {__float2bfloat16(v.x), __float2bfloat16(v.y),
                                    __float2bfloat16(v.z), __float2bfloat16(v.w)};
  *(uint2*)(out + (size_t)i * 4) = *(const uint2*)t;
}

// ------- transpose-cast: dst[b][c][r] = src[b][r][c] * scale  (bf16 out) -------
__global__ __launch_bounds__(256) void transpose_cast_kernel(const float* __restrict__ src,
                                                             __hip_bfloat16* __restrict__ dst,
                                                             int R, int C, float scale) {
  __shared__ float tile[64][65];
  const int r0 = blockIdx.x * 64, c0 = blockIdx.y * 64, bt = blockIdx.z;
  const int tc = threadIdx.x & 63, tr = threadIdx.x >> 6;
  const float* sp = src + (size_t)bt * R * C;
#pragma unroll
  for (int rr = 0; rr < 64; rr += 4)
    tile[tr + rr][tc] = sp[(size_t)(r0 + tr + rr) * C + c0 + tc];
  __syncthreads();
  __hip_bfloat16* dp = dst + (size_t)bt * R * C;
#pragma unroll
  for (int rr = 0; rr < 64; rr += 4) {
    int cc = tr + rr;
    dp[(size_t)(c0 + cc) * R + r0 + tc] = __float2bfloat16(tile[tc][cc] * scale);
  }
}

// ------- fused Wq/Wk/Wv transpose-cast (R=1024, C=64, 16 heads each) -------
__global__ __launch_bounds__(256) void qkv_transpose_kernel(const float* __restrict__ Wq,
                                                            const float* __restrict__ Wk,
                                                            const float* __restrict__ Wv,
                                                            __hip_bfloat16* __restrict__ dst,
                                                            float qscale) {
  __shared__ float tile[64][65];
  const int z = blockIdx.z, which = z >> 4, bt = z & 15;
  const int r0 = blockIdx.x * 64;
  const int tc = threadIdx.x & 63, tr = threadIdx.x >> 6;
  const float* src = (which == 0) ? Wq : (which == 1) ? Wk : Wv;
  const float scale = (which == 0) ? qscale : 1.0f;
  const float* sp = src + (size_t)bt * 1024 * 64;
#pragma unroll
  for (int rr = 0; rr < 64; rr += 4)
    tile[tr + rr][tc] = sp[(size_t)(r0 + tr + rr) * 64 + tc];
  __syncthreads();
  __hip_bfloat16* dp = dst + (size_t)z * 1024 * 64;
#pragma unroll
  for (int rr = 0; rr < 64; rr += 4) {
    int cc = tr + rr;
    dp[(size_t)(cc)*1024 + r0 + tc] = __float2bfloat16(tile[tc][cc] * scale);
  }
}

// ---- QKV GEMM: 256x128 tile, BK=64, 3-slot ring, counted vmcnt (R16) ----
// C[M,3072] = A[M,K] * Bt[3072,K]^T; outputs scattered: Q/K bf16 per-head, Vt packed-T.
// Structure (T3+T4+T5, adapted from the 8-phase template):
//  * 8 waves (512 thr), wave (wm=w>>1, wn=w&1) owns 64x64 of the 256x128 tile,
//    acc[4][4]; ALL waves compute EVERY phase (R9 lesson: never gate on wave id).
//  * LDS = 3 slots x 48KB (A 256x64 = 32KB, B 128x64 = 16KB) = 144KB, 1 block/CU.
//  * Pipeline: computing tile t, tile t+1 fully in flight, tile t+2 being issued.
//    Entry gate per K-tile: vmcnt(6) (= exactly tile t+1's 6 loads/thread younger)
//    + raw s_barrier — loads stay in flight across barriers, NEVER vmcnt(0).
//  * 2 phases/K-tile: ph0 {stage A of t+2 (4 ld); ds_read bv(8)+av01(4); 16 MFMA},
//    ph1 {stage B of t+2 (2 ld); ds_read av23(4); 16 MFMA}; raw s_barrier between.
//  * Ledger: per-thread 6 loads/tile, order A,A,A,A,B,B. At gate of tile t the 6
//    newest are tile t+1's -> vmcnt(6) waits exactly for tile t. Last 2 iters
//    re-stage tile 15 (dummy, into the to-be-unused slot) to keep counts uniform.
//  * WAR: stage targets slot (t+2)%3 = slot of tile t-1, whose reads all finished
//    before this tile's entry barrier. ds_reads can't cross the asm "memory" gates.
//  * chunk-XOR swizzle (g=row&7) via pre-swizzled global source + swizzled ds_read
//    (both-sides rule #21; same pattern as flash) -> 2-way LDS conflicts (free).
__global__ __launch_bounds__(512, 2) void gemm256_qkv(const __hip_bfloat16* __restrict__ A,
                                                      const __hip_bfloat16* __restrict__ Bt,
                                                      __hip_bfloat16* __restrict__ outQ,
                                                      __hip_bfloat16* __restrict__ outK,
                                                      __hip_bfloat16* __restrict__ outV,
                                                      int M, int N, int K) {
  __shared__ __hip_bfloat16 lds[3 * 24576];  // 144KB
  const int tid = threadIdx.x;
  const int lane = tid & 63, w = tid >> 6;
  const int lr = lane & 15, lq = lane >> 4;
  const int wm = w >> 1, wn = w & 1;  // wm 0..3 (64-row band), wn 0..1 (64-col band)
  const int gk = lr & 7;
  // bijective XCD swizzle: 768 blocks; XCD k owns by-chunk [4k,4k+4), bx fastest.
  const int nlin = blockIdx.x + gridDim.x * blockIdx.y;
  const int xcd = nlin & 7, sid = nlin >> 3;  // sid 0..95
  const int bx = sid >> 2;                    // 0..23
  const int by = xcd * 4 + (sid & 3);         // 0..31
  const int m0 = by * 256, n0 = bx * 128;

  const f32x4 fz = {0.f, 0.f, 0.f, 0.f};
  f32x4 acc[4][4];
#pragma unroll
  for (int i = 0; i < 4; i++)
#pragma unroll
    for (int j = 0; j < 4; j++) acc[i][j] = fz;

  // stage A half of tile tt into slot sl: 256 rows x 8 chunks, 4 loads/thread
  auto stageA = [&](int tt, int sl) {
#pragma unroll
    for (int r = 0; r < 4; r++) {
      const int c = r * 512 + tid;
      const int row = c >> 3, ck = c & 7;
      async_load16((const short*)A + (size_t)(m0 + row) * K + tt * 64 + ((ck ^ (row & 7)) * 8),
                   (char*)lds + sl * 49152 + (r * 512 + (tid & 0x1C0)) * 16);
    }
  };
  // stage B of tile tt: 128 rows x 8 chunks, 2 loads/thread
  auto stageB = [&](int tt, int sl) {
#pragma unroll
    for (int r = 0; r < 2; r++) {
      const int c = r * 512 + tid;
      const int row = c >> 3, ck = c & 7;
      async_load16((const short*)Bt + (size_t)(n0 + row) * K + tt * 64 + ((ck ^ (row & 7)) * 8),
                   (char*)lds + sl * 49152 + 32768 + (r * 512 + (tid & 0x1C0)) * 16);
    }
  };

  // prologue: tiles 0,1 -> slots 0,1 (issue order A,A,A,A,B,B per tile)
  stageA(0, 0); stageB(0, 0);
  stageA(1, 1); stageB(1, 1);

  const int kiters = K >> 6;  // 16
  int slot = 0;
  for (int t = 0; t < kiters; t++) {
    const short* Ap = (const short*)lds + slot * 24576;
    const short* Bp = Ap + 16384;
    const int tt = (t + 2 < kiters) ? t + 2 : kiters - 1;  // clamp: dummy re-stage
    int sln = slot + 2; if (sln >= 3) sln -= 3;            // (t+2)%3 = tile t-1's slot (freed)

    // ENTRY GATE: wait own tile-t loads (6 newest = t+1's stay in flight), then barrier.
    asm volatile("s_waitcnt vmcnt(6)\n\ts_barrier" ::: "memory");

    // ---- phase 0: stage A(t+2); read bv + av[0..1]; 16 MFMA (i=0,1) ----
    stageA(tt, sln);
    s16x8 bv[4][2], av0[2][2];
#pragma unroll
    for (int j = 0; j < 4; j++)
#pragma unroll
      for (int ks = 0; ks < 2; ks++)
        bv[j][ks] = *(const s16x8*)(Bp + (wn * 64 + j * 16 + lr) * 64 + (((ks * 4 + lq) ^ gk)) * 8);
#pragma unroll
    for (int i = 0; i < 2; i++)
#pragma unroll
      for (int ks = 0; ks < 2; ks++)
        av0[i][ks] = *(const s16x8*)(Ap + (wm * 64 + i * 16 + lr) * 64 + (((ks * 4 + lq) ^ gk)) * 8);
    __builtin_amdgcn_s_setprio(1);
#pragma unroll
    for (int ks = 0; ks < 2; ks++)
#pragma unroll
      for (int i = 0; i < 2; i++)
#pragma unroll
      for (int j = 0; j < 4; j++)
        acc[i][j] = __builtin_amdgcn_mfma_f32_16x16x32_bf16(av0[i][ks], bv[j][ks], acc[i][j], 0, 0, 0);
    __builtin_amdgcn_s_setprio(0);
    asm volatile("s_barrier" ::: "memory");

    // ---- phase 1: stage B(t+2); read av[2..3]; 16 MFMA (i=2,3) ----
    stageB(tt, sln);
    s16x8 av1[2][2];
#pragma unroll
    for (int i = 0; i < 2; i++)
#pragma unroll
      for (int ks = 0; ks < 2; ks++)
        av1[i][ks] =
            *(const s16x8*)(Ap + (wm * 64 + (2 + i) * 16 + lr) * 64 + (((ks * 4 + lq) ^ gk)) * 8);
    __builtin_amdgcn_s_setprio(1);
#pragma unroll
    for (int ks = 0; ks < 2; ks++)
#pragma unroll
      for (int i = 0; i < 2; i++)
#pragma unroll
      for (int j = 0; j < 4; j++)
        acc[2 + i][j] =
            __builtin_amdgcn_mfma_f32_16x16x32_bf16(av1[i][ks], bv[j][ks], acc[2 + i][j], 0, 0, 0);
    __builtin_amdgcn_s_setprio(0);
    asm volatile("s_barrier" ::: "memory");

    slot = slot + 1; if (slot == 3) slot = 0;
  }

  // epilogue (block-uniform branch: bx<8 Q, <16 K, else V)
  if (n0 < 2048) {
    __hip_bfloat16* dst01 = (n0 < 1024) ? outQ : outK;
#pragma unroll
    for (int i = 0; i < 4; i++)
#pragma unroll
      for (int j = 0; j < 4; j++)
#pragma unroll
        for (int r = 0; r < 4; r++) {
          const int row = m0 + wm * 64 + i * 16 + lq * 4 + r;
          const int col = n0 + wn * 64 + j * 16 + lr;
          const int bb = row >> 11, s = row & 2047;
          const int colq = col & 1023;
          dst01[((((size_t)bb * 16 + (colq >> 6)) * 2048 + s) << 6) + (col & 63)] =
              __float2bfloat16(acc[i][j][r]);
        }
  } else {
#pragma unroll
    for (int i = 0; i < 4; i++)
#pragma unroll
      for (int j = 0; j < 4; j++) {
        const int row0 = m0 + wm * 64 + i * 16 + lq * 4;
        const int col = (n0 - 2048) + wn * 64 + j * 16 + lr;  // dh-global 0..1023
        const int bb = row0 >> 11, s0 = row0 & 2047;
        alignas(8) __hip_bfloat16 t4[4] = {
            __float2bfloat16(acc[i][j][0]), __float2bfloat16(acc[i][j][1]),
            __float2bfloat16(acc[i][j][2]), __float2bfloat16(acc[i][j][3])};
        *(uint2*)(outV + (size_t)bb * 2097152 + (size_t)col * 2048 + s0) = *(const uint2*)t4;
      }
  }
}

// ---------------- 128x128 bf16 MFMA GEMM, BK=32, m97 structure (R7 proven) ----------------
// Used for the output projection (MODE 2): fp32 out0 = acc + bias[col] + resid.
template <int MODE>
__global__ __launch_bounds__(256) void gemm128(const __hip_bfloat16* __restrict__ A,
                                               const __hip_bfloat16* __restrict__ Bt,
                                               void* __restrict__ out0,
                                               void* __restrict__ out1,
                                               void* __restrict__ out2,
                                               const float* __restrict__ bias,
                                               const float* __restrict__ resid,
                                               int M, int N, int K) {
  __shared__ __hip_bfloat16 As[128 * 32];
  __shared__ __hip_bfloat16 Bs[128 * 32];
  const int tid = threadIdx.x;
  const int lane = tid & 63, w = tid >> 6;
  const int lr = lane & 15, lq = lane >> 4;
  const int wm = w >> 1, wn = w & 1;
  const int nlin = blockIdx.x + gridDim.x * blockIdx.y;
  const int xcd = nlin & 7, slot = nlin >> 3;
  const int bx = slot >> 3;
  const int by = xcd * 8 + (slot & 7);
  const int m0 = by * 128, n0 = bx * 128;

  const f32x4 fz = {0.f, 0.f, 0.f, 0.f};
  f32x4 acc[4][4];
#pragma unroll
  for (int i = 0; i < 4; i++)
#pragma unroll
    for (int j = 0; j < 4; j++) acc[i][j] = fz;

  const int kiters = K >> 5;
  for (int kt = 0; kt < kiters; kt++) {
    __syncthreads();
#pragma unroll
    for (int r = 0; r < 2; r++) {
      const int c = r * 256 + tid;
      const int row = c >> 2, kc = c & 3;
      async_load16((const short*)A + (size_t)(m0 + row) * K + kt * 32 + kc * 8,
                   (char*)As + (r * 256 + (tid & 0xC0)) * 16);
      async_load16((const short*)Bt + (size_t)(n0 + row) * K + kt * 32 + kc * 8,
                   (char*)Bs + (r * 256 + (tid & 0xC0)) * 16);
    }
    __syncthreads();
    const short* Ap = (const short*)As;
    const short* Bp = (const short*)Bs;
    s16x8 av[4], bv[4];
#pragma unroll
    for (int i = 0; i < 4; i++)
      av[i] = *(const s16x8*)(Ap + (wm * 64 + i * 16 + lr) * 32 + lq * 8);
#pragma unroll
    for (int j = 0; j < 4; j++)
      bv[j] = *(const s16x8*)(Bp + (wn * 64 + j * 16 + lr) * 32 + lq * 8);
#pragma unroll
    for (int i = 0; i < 4; i++)
#pragma unroll
      for (int j = 0; j < 4; j++)
        acc[i][j] = __builtin_amdgcn_mfma_f32_16x16x32_bf16(av[i], bv[j], acc[i][j], 0, 0, 0);
  }

#pragma unroll
  for (int i = 0; i < 4; i++)
#pragma unroll
    for (int j = 0; j < 4; j++)
#pragma unroll
      for (int r = 0; r < 4; r++) {
        const int row = m0 + wm * 64 + i * 16 + lq * 4 + r;
        const int col = n0 + wn * 64 + j * 16 + lr;
        const size_t idx = (size_t)row * 1024 + col;
        ((float*)out0)[idx] = acc[i][j][r] + bias[col] + resid[idx];
      }
}

// ------------- streaming-softmax attention: 4-wave blocks, 32 q/wave -------------
// (R3 kernel, verbatim — best measured flash: 88.0us, VGPR 52, Occ 35%.)
// R10 lesson: NEVER cap VGPR below live state via launch_bounds — (256,7) forced
// spills of o/ol/qb to scratch (1.85GB HBM traffic, 5x slowdown). (256,4) is right.
// R9: 4 waves; wave pair (w>>1) owns q-tile pair; (w&1) picks 32-kv half.
// R7: double-buffered K/V staging. R8: row-sum on the MFMA pipe (ones-MFMA).
// R4: TLP >> per-wave ILP. R5: LDS staging IS the coalescer.
// CRITICAL (R6): register arrays never runtime-indexed (scratch demotion).
// Grid x=hb: XCD = blockid%8 = hb%8 -> all 32 qt of one (b,h) share K/V in one L2.
__global__ __launch_bounds__(256, 4) void flash_kernel(const __hip_bfloat16* __restrict__ Qg,
                                                       const __hip_bfloat16* __restrict__ Kg,
                                                       const __hip_bfloat16* __restrict__ Vtg,
                                                       __hip_bfloat16* __restrict__ Og) {
  __shared__ alignas(16) char smem[32768];
  float* xch = (float*)smem;  // slot stride 1280 f32: 1024 o + 256 ol
  const int tid = threadIdx.x;
  const int lane = tid & 63, w = tid >> 6;
  const int lr = lane & 15, lq = lane >> 4;
  const int qp = w >> 1;
  const int kvh = w & 1;
  const int hb = blockIdx.x, qt = blockIdx.y;
  const int h = hb >> 2, b = hb & 3;
  const size_t bh = (size_t)b * 16 + h;
  const short* Qbase = (const short*)Qg + (bh * 2048 + (size_t)qt * 64) * 64;
  const short* Kbh = (const short*)Kg + bh * 2048 * 64;
  const short* Vbh = (const short*)Vtg + bh * 64 * 2048;

  const int rbase = (lr >> 2) * 8 + (lr & 3);
  const int gk = lr & 7;

  s16x8 qb[2][2];
#pragma unroll
  for (int ntl = 0; ntl < 2; ntl++)
#pragma unroll
    for (int ks = 0; ks < 2; ks++)
      qb[ntl][ks] =
          *(const s16x8*)(Qbase + ((qp * 2 + ntl) * 16 + lr) * 64 + ks * 32 + lq * 8);

  s16x8 vones;
#pragma unroll
  for (int e = 0; e < 8; e++) vones[e] = (short)0x3F80;

  const f32x4 fz = {0.f, 0.f, 0.f, 0.f};
  f32x4 o[2][4];
  f32x4 ol[2];
#pragma unroll
  for (int i = 0; i < 2; i++) {
    ol[i] = fz;
#pragma unroll
    for (int j = 0; j < 4; j++) o[i][j] = fz;
  }

  auto stage = [&](int sel, int kb) {
    char* Kl = smem + sel * 16384;
    char* Vl = Kl + 8192;
    const short* Ksrc = Kbh + kb * 64 * 64;
#pragma unroll
    for (int r = 0; r < 2; r++) {
      int c = r * 256 + tid;
      int row = c >> 3, ck = c & 7;
      int g = (row & 3) | (((row >> 3) & 1) << 2);
      async_load16(Ksrc + row * 64 + (ck ^ g) * 8, Kl + (r * 256 + (tid & 0xC0)) * 16);
    }
#pragma unroll
    for (int r = 0; r < 2; r++) {
      int c = r * 256 + tid;
      int row = c >> 3, ck = c & 7;
      async_load16(Vbh + (size_t)row * 2048 + kb * 64 + ((ck ^ (row & 7))) * 8,
                   Vl + (r * 256 + (tid & 0xC0)) * 16);
    }
  };

  stage(0, 0);
  __syncthreads();

  for (int kb = 0; kb < 32; kb++) {
    const int cur = kb & 1;
    if (kb + 1 < 32) stage(cur ^ 1, kb + 1);

    const short* Kp = (const short*)(smem + cur * 16384);
    const short* Vp = (const short*)(smem + cur * 16384 + 8192);

    union { i32x4 i; s16x8 s; } pa[2];
#pragma unroll
    for (int mt = 0; mt < 2; mt++) {
      const int kvrow = kvh * 32 + mt * 4 + rbase;
      s16x8 kf0 = *(const s16x8*)(Kp + kvrow * 64 + (((0 * 4 + lq) ^ gk)) * 8);
      s16x8 kf1 = *(const s16x8*)(Kp + kvrow * 64 + (((1 * 4 + lq) ^ gk)) * 8);
#pragma unroll
      for (int ntl = 0; ntl < 2; ntl++) {
        f32x4 st = fz;
        st = __builtin_amdgcn_mfma_f32_16x16x32_bf16(kf0, qb[ntl][0], st, 0, 0, 0);
        st = __builtin_amdgcn_mfma_f32_16x16x32_bf16(kf1, qb[ntl][1], st, 0, 0, 0);
        float e0 = __builtin_amdgcn_exp2f(st[0]);
        float e1 = __builtin_amdgcn_exp2f(st[1]);
        float e2 = __builtin_amdgcn_exp2f(st[2]);
        float e3 = __builtin_amdgcn_exp2f(st[3]);
        pa[ntl].i[mt * 2 + 0] = (int)pack_bf16x2(e0, e1);
        pa[ntl].i[mt * 2 + 1] = (int)pack_bf16x2(e2, e3);
      }
    }
    __builtin_amdgcn_s_setprio(1);
#pragma unroll
    for (int ntl = 0; ntl < 2; ntl++)
      ol[ntl] = __builtin_amdgcn_mfma_f32_16x16x32_bf16(pa[ntl].s, vones, ol[ntl], 0, 0, 0);
#pragma unroll
    for (int ndh = 0; ndh < 4; ndh++) {
      int vrow = ndh * 16 + lr;
      s16x8 vb = *(const s16x8*)(Vp + vrow * 64 + (((kvh * 4 + lq) ^ (vrow & 7))) * 8);
#pragma unroll
      for (int ntl = 0; ntl < 2; ntl++)
        o[ntl][ndh] =
            __builtin_amdgcn_mfma_f32_16x16x32_bf16(pa[ntl].s, vb, o[ntl][ndh], 0, 0, 0);
    }
    __builtin_amdgcn_s_setprio(0);

    __syncthreads();
  }

  float* slot = xch + w * 1280;
  if (kvh == 0) {
#pragma unroll
    for (int ndh = 0; ndh < 4; ndh++)
      *(f32x4*)(slot + ndh * 256 + lane * 4) = o[1][ndh];
    *(f32x4*)(slot + 1024 + lane * 4) = ol[1];
  } else {
#pragma unroll
    for (int ndh = 0; ndh < 4; ndh++)
      *(f32x4*)(slot + ndh * 256 + lane * 4) = o[0][ndh];
    *(f32x4*)(slot + 1024 + lane * 4) = ol[0];
  }
  __syncthreads();
  const float* ps = xch + (w ^ 1) * 1280;
  if (kvh == 0) {
#pragma unroll
    for (int ndh = 0; ndh < 4; ndh++)
      o[0][ndh] += *(const f32x4*)(ps + ndh * 256 + lane * 4);
    f32x4 lt = ol[0] + *(const f32x4*)(ps + 1024 + lane * 4);
#pragma unroll
    for (int r = 0; r < 4; r++) {
      float inv = __builtin_amdgcn_rcpf(lt[r]);
      int rowg = qt * 64 + w * 16 + lq * 4 + r;
#pragma unroll
      for (int ndh = 0; ndh < 4; ndh++)
        Og[((size_t)b * 2048 + rowg) * 1024 + h * 64 + ndh * 16 + lr] =
            __float2bfloat16(o[0][ndh][r] * inv);
    }
  } else {
#pragma unroll
    for (int ndh = 0; ndh < 4; ndh++)
      o[1][ndh] += *(const f32x4*)(ps + ndh * 256 + lane * 4);
    f32x4 lt = ol[1] + *(const f32x4*)(ps + 1024 + lane * 4);
#pragma unroll
    for (int r = 0; r < 4; r++) {
      float inv = __builtin_amdgcn_rcpf(lt[r]);
      int rowg = qt * 64 + w * 16 + lq * 4 + r;
#pragma unroll
      for (int ndh = 0; ndh < 4; ndh++)
        Og[((size_t)b * 2048 + rowg) * 1024 + h * 64 + ndh * 16 + lr] =
            __float2bfloat16(o[1][ndh][r] * inv);
    }
  }
}

// ---------------- LayerNorm over last dim (1024) ----------------
__global__ __launch_bounds__(256) void ln_kernel(const float* __restrict__ tmp,
                                                 const float* __restrict__ gamma,
                                                 const float* __restrict__ beta,
                                                 float* __restrict__ out) {
  const int row = blockIdx.x, tid = threadIdx.x;
  const int lane = tid & 63, w = tid >> 6;
  const float* rp = tmp + (size_t)row * 1024;
  float4 v = ((const float4*)rp)[tid];
  float s = v.x + v.y + v.z + v.w;
  float ss = v.x * v.x + v.y * v.y + v.z * v.z + v.w * v.w;
#pragma unroll
  for (int off = 32; off >= 1; off >>= 1) {
    s += __shfl_xor(s, off);
    ss += __shfl_xor(ss, off);
  }
  __shared__ float red[8];
  if (lane == 0) {
    red[w] = s;
    red[4 + w] = ss;
  }
  __syncthreads();
  s = red[0] + red[1] + red[2] + red[3];
  ss = red[4] + red[5] + red[6] + red[7];
  const float mu = s * (1.0f / 1024.0f);
  const float var = ss * (1.0f / 1024.0f) - mu * mu;
  const float rstd = rsqrtf(var + 1e-5f);
  float4 g = ((const float4*)gamma)[tid];
  float4 be = ((const float4*)beta)[tid];
  float4 ov;
  ov.x = (v.x - mu) * rstd * g.x + be.x;
  ov.y = (v.y - mu) * rstd * g.y + be.y;
  ov.z = (v.z - mu) * rstd * g.z + be.z;
  ov.w = (v.w - mu) * rstd * g.w + be.w;
  ((float4*)(out + (size_t)row * 1024))[tid] = ov;
}

extern "C" void kernel_launch(void* const* d_in, const int* in_sizes, int n_in,
                              void* d_out, int out_size, void* d_ws, size_t ws_size,
                              hipStream_t stream) {
  (void)in_sizes; (void)n_in; (void)out_size; (void)ws_size;
  const float* x = (const float*)d_in[0];
  const float* Wq = (const float*)d_in[1];
  const float* Wk = (const float*)d_in[2];
  const float* Wv = (const float*)d_in[3];
  const float* Wo = (const float*)d_in[4];
  const float* bo = (const float*)d_in[5];
  const float* gamma = (const float*)d_in[6];
  const float* beta = (const float*)d_in[7];
  float* out = (float*)d_out;
  char* ws = (char*)d_ws;

  // workspace layout (bytes)
  __hip_bfloat16* xb = (__hip_bfloat16*)(ws + 0);          // 16 MB  [8192][1024]
  __hip_bfloat16* wqkvT = (__hip_bfloat16*)(ws + 16777216);// 6 MB   [3072][1024] (Wq x 0.125*log2e)
  __hip_bfloat16* woT = (__hip_bfloat16*)(ws + 23068672);  // 2 MB
  __hip_bfloat16* Q = (__hip_bfloat16*)(ws + 25165824);    // 16 MB [B,H,S,64]
  __hip_bfloat16* Kt = (__hip_bfloat16*)(ws + 41943040);   // 16 MB [B,H,S,64]
  __hip_bfloat16* Vt = (__hip_bfloat16*)(ws + 58720256);   // 16 MB [B,H,64,S]
  __hip_bfloat16* cc = (__hip_bfloat16*)(ws + 75497472);   // 16 MB [B,S,1024]
  float* tmp = (float*)(ws + 25165824);  // 32 MB fp32, aliases dead Q+Kt (stream-ordered)

  cast_x_kernel<<<8192, 256, 0, stream>>>(x, xb, 2097152);
  // Q scale folds 1/sqrt(64) and log2(e) so flash can use raw v_exp_f32 (exp2)
  qkv_transpose_kernel<<<dim3(16, 1, 48), 256, 0, stream>>>(Wq, Wk, Wv, wqkvT,
                                                            0.125f * 1.44269504088896f);
  transpose_cast_kernel<<<dim3(16, 16, 1), 256, 0, stream>>>(Wo, woT, 1024, 1024, 1.0f);

  // fused QKV projection: Bt = [wqT ; wkT ; wvT] (3072 rows, contiguous)
  gemm256_qkv<<<dim3(24, 32), 512, 0, stream>>>(xb, wqkvT, Q, Kt, Vt, 8192, 3072, 1024);

  flash_kernel<<<dim3(64, 32), 256, 0, stream>>>(Q, Kt, Vt, cc);

  gemm128<2><<<dim3(8, 64), 256, 0, stream>>>(cc, woT, tmp, nullptr, nullptr, bo, x,
                                              8192, 1024, 1024);
  ln_kernel<<<8192, 256, 0, stream>>>(tmp, gamma, beta, out);
}

// Round 12
// 286.571 us; speedup vs baseline: 2.3351x; 1.0337x over previous
//
#include <hip/hip_runtime.h>
#include <hip/hip_bf16.h>
#include <stdint.h>

#define DEV __device__ __forceinline__

typedef short s16x8 __attribute__((ext_vector_type(8)));
typedef float f32x4 __attribute__((ext_vector_type(4)));
typedef int i32x4 __attribute__((ext_vector_type(4)));

// async 16B global->LDS. LDS side is wave-uniform base + lane*16 (HW rule).
DEV void async_load16(const void* g, void* l) {
  __builtin_amdgcn_global_load_lds((void __attribute__((address_space(1)))*)(g),
                                   (void __attribute__((address_space(3)))*)(l),
                                   16, 0, 0);
}

DEV unsigned pack_bf16x2(float a, float b) {
  __hip_bfloat162 h = __float22bfloat162_rn(make_float2(a, b));
  union { __hip_bfloat162 h2; unsigned u; } cv;
  cv.h2 = h;
  return cv.u;
}

// ---------------- cast x fp32 -> bf16 ----------------
__global__ __launch_bounds__(256) void cast_x_kernel(const float* __restrict__ in,
                                                     __hip_bfloat16* __restrict__ out, int n4) {
  int i = blockIdx.x * 256 + threadIdx.x;
  if (i >= n4) return;
  float4 v = ((const float4*)in)[i];
  alignas(8) __hip_bfloat16 t[4] = {__float2bfloat16(v.x), __float2bfloat16(v.y),
                                    __float2bfloat16(v.z), __float2bfloat16(v.w)};
  *(uint2*)(out + (size_t)i * 4) = *(const uint2*)t;
}

// ------- transpose-cast: dst[b][c][r] = src[b][r][c] * scale  (bf16 out) -------
__global__ __launch_bounds__(256) void transpose_cast_kernel(const float* __restrict__ src,
                                                             __hip_bfloat16* __restrict__ dst,
                                                             int R, int C, float scale) {
  __shared__ float tile[64][65];
  const int r0 = blockIdx.x * 64, c0 = blockIdx.y * 64, bt = blockIdx.z;
  const int tc = threadIdx.x & 63, tr = threadIdx.x >> 6;
  const float* sp = src + (size_t)bt * R * C;
#pragma unroll
  for (int rr = 0; rr < 64; rr += 4)
    tile[tr + rr][tc] = sp[(size_t)(r0 + tr + rr) * C + c0 + tc];
  __syncthreads();
  __hip_bfloat16* dp = dst + (size_t)bt * R * C;
#pragma unroll
  for (int rr = 0; rr < 64; rr += 4) {
    int cc = tr + rr;
    dp[(size_t)(c0 + cc) * R + r0 + tc] = __float2bfloat16(tile[tc][cc] * scale);
  }
}

// ------- fused Wq/Wk/Wv transpose-cast (R=1024, C=64, 16 heads each) -------
__global__ __launch_bounds__(256) void qkv_transpose_kernel(const float* __restrict__ Wq,
                                                            const float* __restrict__ Wk,
                                                            const float* __restrict__ Wv,
                                                            __hip_bfloat16* __restrict__ dst,
                                                            float qscale) {
  __shared__ float tile[64][65];
  const int z = blockIdx.z, which = z >> 4, bt = z & 15;
  const int r0 = blockIdx.x * 64;
  const int tc = threadIdx.x & 63, tr = threadIdx.x >> 6;
  const float* src = (which == 0) ? Wq : (which == 1) ? Wk : Wv;
  const float scale = (which == 0) ? qscale : 1.0f;
  const float* sp = src + (size_t)bt * 1024 * 64;
#pragma unroll
  for (int rr = 0; rr < 64; rr += 4)
    tile[tr + rr][tc] = sp[(size_t)(r0 + tr + rr) * 64 + tc];
  __syncthreads();
  __hip_bfloat16* dp = dst + (size_t)z * 1024 * 64;
#pragma unroll
  for (int rr = 0; rr < 64; rr += 4) {
    int cc = tr + rr;
    dp[(size_t)(cc)*1024 + r0 + tc] = __float2bfloat16(tile[tc][cc] * scale);
  }
}

// ---- 256x128 tile, BK=64, 3-slot ring, counted vmcnt (R16; refcheck'd R11) ----
// C[M,N] = A[M,K] * Bt[N,K]^T.
// MODE 0 (QKV, N=3072, grid 24x32): cols<1024 -> Q, <2048 -> K, >=2048 -> Vt packed-T.
// MODE 2 (out-proj, N=1024, grid 8x32): fp32 out0 = acc + bias[col] + resid.  (R17)
// Structure (T3+T4+T5):
//  * 8 waves (512 thr), wave (wm,wn) owns 64x64; ALL waves compute EVERY phase.
//  * LDS = 3 slots x 48KB (A 256x64=32KB, B 128x64=16KB) = 144KB, 1 block/CU.
//  * Computing tile t, t+1 fully in flight, t+2 being issued. Entry gate:
//    vmcnt(6) (exactly t+1's 6 loads/thread younger) + raw s_barrier — never vmcnt(0).
//  * 2 phases/K-tile: ph0 {stage A(t+2); ds_read bv+av01; 16 MFMA},
//    ph1 {stage B(t+2); ds_read av23; 16 MFMA}; raw s_barrier between.
//  * Ledger: 6 loads/thread/tile, order A,A,A,A,B,B; last 2 iters dummy re-stage.
//  * WAR: stage targets slot (t+2)%3 = tile t-1's slot (reads done pre-gate).
//  * chunk-XOR swizzle (g=row&7) both-sides (rule #21) -> 2-way conflicts (free).
template <int MODE>
__global__ __launch_bounds__(512, 2) void gemm256(const __hip_bfloat16* __restrict__ A,
                                                  const __hip_bfloat16* __restrict__ Bt,
                                                  void* __restrict__ out0,
                                                  void* __restrict__ out1,
                                                  void* __restrict__ out2,
                                                  const float* __restrict__ bias,
                                                  const float* __restrict__ resid,
                                                  int M, int N, int K) {
  __shared__ __hip_bfloat16 lds[3 * 24576];  // 144KB
  const int tid = threadIdx.x;
  const int lane = tid & 63, w = tid >> 6;
  const int lr = lane & 15, lq = lane >> 4;
  const int wm = w >> 1, wn = w & 1;
  const int gk = lr & 7;
  // bijective XCD swizzle: XCD k owns by-chunk [4k,4k+4), bx fastest.
  const int nlin = blockIdx.x + gridDim.x * blockIdx.y;
  const int xcd = nlin & 7, sid = nlin >> 3;
  const int bx = sid >> 2;
  const int by = xcd * 4 + (sid & 3);
  const int m0 = by * 256, n0 = bx * 128;

  const f32x4 fz = {0.f, 0.f, 0.f, 0.f};
  f32x4 acc[4][4];
#pragma unroll
  for (int i = 0; i < 4; i++)
#pragma unroll
    for (int j = 0; j < 4; j++) acc[i][j] = fz;

  auto stageA = [&](int tt, int sl) {
#pragma unroll
    for (int r = 0; r < 4; r++) {
      const int c = r * 512 + tid;
      const int row = c >> 3, ck = c & 7;
      async_load16((const short*)A + (size_t)(m0 + row) * K + tt * 64 + ((ck ^ (row & 7)) * 8),
                   (char*)lds + sl * 49152 + (r * 512 + (tid & 0x1C0)) * 16);
    }
  };
  auto stageB = [&](int tt, int sl) {
#pragma unroll
    for (int r = 0; r < 2; r++) {
      const int c = r * 512 + tid;
      const int row = c >> 3, ck = c & 7;
      async_load16((const short*)Bt + (size_t)(n0 + row) * K + tt * 64 + ((ck ^ (row & 7)) * 8),
                   (char*)lds + sl * 49152 + 32768 + (r * 512 + (tid & 0x1C0)) * 16);
    }
  };

  // prologue: tiles 0,1 -> slots 0,1 (issue order A,A,A,A,B,B per tile)
  stageA(0, 0); stageB(0, 0);
  stageA(1, 1); stageB(1, 1);

  const int kiters = K >> 6;  // 16
  int slot = 0;
  for (int t = 0; t < kiters; t++) {
    const short* Ap = (const short*)lds + slot * 24576;
    const short* Bp = Ap + 16384;
    const int tt = (t + 2 < kiters) ? t + 2 : kiters - 1;  // clamp: dummy re-stage
    int sln = slot + 2; if (sln >= 3) sln -= 3;

    // ENTRY GATE: wait own tile-t loads (t+1's 6 stay in flight), then barrier.
    asm volatile("s_waitcnt vmcnt(6)\n\ts_barrier" ::: "memory");

    // ---- phase 0: stage A(t+2); read bv + av[0..1]; 16 MFMA ----
    stageA(tt, sln);
    s16x8 bv[4][2], av0[2][2];
#pragma unroll
    for (int j = 0; j < 4; j++)
#pragma unroll
      for (int ks = 0; ks < 2; ks++)
        bv[j][ks] = *(const s16x8*)(Bp + (wn * 64 + j * 16 + lr) * 64 + (((ks * 4 + lq) ^ gk)) * 8);
#pragma unroll
    for (int i = 0; i < 2; i++)
#pragma unroll
      for (int ks = 0; ks < 2; ks++)
        av0[i][ks] = *(const s16x8*)(Ap + (wm * 64 + i * 16 + lr) * 64 + (((ks * 4 + lq) ^ gk)) * 8);
    __builtin_amdgcn_s_setprio(1);
#pragma unroll
    for (int ks = 0; ks < 2; ks++)
#pragma unroll
      for (int i = 0; i < 2; i++)
#pragma unroll
      for (int j = 0; j < 4; j++)
        acc[i][j] = __builtin_amdgcn_mfma_f32_16x16x32_bf16(av0[i][ks], bv[j][ks], acc[i][j], 0, 0, 0);
    __builtin_amdgcn_s_setprio(0);
    asm volatile("s_barrier" ::: "memory");

    // ---- phase 1: stage B(t+2); read av[2..3]; 16 MFMA ----
    stageB(tt, sln);
    s16x8 av1[2][2];
#pragma unroll
    for (int i = 0; i < 2; i++)
#pragma unroll
      for (int ks = 0; ks < 2; ks++)
        av1[i][ks] =
            *(const s16x8*)(Ap + (wm * 64 + (2 + i) * 16 + lr) * 64 + (((ks * 4 + lq) ^ gk)) * 8);
    __builtin_amdgcn_s_setprio(1);
#pragma unroll
    for (int ks = 0; ks < 2; ks++)
#pragma unroll
      for (int i = 0; i < 2; i++)
#pragma unroll
      for (int j = 0; j < 4; j++)
        acc[2 + i][j] =
            __builtin_amdgcn_mfma_f32_16x16x32_bf16(av1[i][ks], bv[j][ks], acc[2 + i][j], 0, 0, 0);
    __builtin_amdgcn_s_setprio(0);
    asm volatile("s_barrier" ::: "memory");

    slot = slot + 1; if (slot == 3) slot = 0;
  }

  if constexpr (MODE == 0) {
    // epilogue (block-uniform branch: bx<8 Q, <16 K, else V)
    if (n0 < 2048) {
      __hip_bfloat16* dst01 = (__hip_bfloat16*)((n0 < 1024) ? out0 : out1);
#pragma unroll
      for (int i = 0; i < 4; i++)
#pragma unroll
        for (int j = 0; j < 4; j++)
#pragma unroll
          for (int r = 0; r < 4; r++) {
            const int row = m0 + wm * 64 + i * 16 + lq * 4 + r;
            const int col = n0 + wn * 64 + j * 16 + lr;
            const int bb = row >> 11, s = row & 2047;
            const int colq = col & 1023;
            dst01[((((size_t)bb * 16 + (colq >> 6)) * 2048 + s) << 6) + (col & 63)] =
                __float2bfloat16(acc[i][j][r]);
          }
    } else {
#pragma unroll
      for (int i = 0; i < 4; i++)
#pragma unroll
        for (int j = 0; j < 4; j++) {
          const int row0 = m0 + wm * 64 + i * 16 + lq * 4;
          const int col = (n0 - 2048) + wn * 64 + j * 16 + lr;  // dh-global 0..1023
          const int bb = row0 >> 11, s0 = row0 & 2047;
          alignas(8) __hip_bfloat16 t4[4] = {
              __float2bfloat16(acc[i][j][0]), __float2bfloat16(acc[i][j][1]),
              __float2bfloat16(acc[i][j][2]), __float2bfloat16(acc[i][j][3])};
          *(uint2*)((__hip_bfloat16*)out2 + (size_t)bb * 2097152 + (size_t)col * 2048 + s0) =
              *(const uint2*)t4;
        }
    }
  } else {
#pragma unroll
    for (int i = 0; i < 4; i++)
#pragma unroll
      for (int j = 0; j < 4; j++)
#pragma unroll
        for (int r = 0; r < 4; r++) {
          const int row = m0 + wm * 64 + i * 16 + lq * 4 + r;
          const int col = n0 + wn * 64 + j * 16 + lr;
          const size_t idx = (size_t)row * 1024 + col;
          ((float*)out0)[idx] = acc[i][j][r] + bias[col] + resid[idx];
        }
  }
}

// ------------- streaming-softmax attention: 4-wave blocks, 32 q/wave -------------
// (R3 kernel, verbatim — best measured flash: 88.0-92.0us, VGPR 52, Occ ~34%.)
// R10 lesson: NEVER cap VGPR below live state via launch_bounds ((256,7) spilled
// accumulators -> 1.85GB scratch traffic, 5x). (256,4) is right.
// R9: 4 waves; wave pair (w>>1) owns q-tile pair; (w&1) picks 32-kv half.
// R7: double-buffered K/V staging. R8: row-sum on the MFMA pipe (ones-MFMA).
// R4: TLP >> per-wave ILP. R5: LDS staging IS the coalescer.
// CRITICAL (R6): register arrays never runtime-indexed (scratch demotion).
// Grid x=hb: XCD = blockid%8 = hb%8 -> all 32 qt of one (b,h) share K/V in one L2.
__global__ __launch_bounds__(256, 4) void flash_kernel(const __hip_bfloat16* __restrict__ Qg,
                                                       const __hip_bfloat16* __restrict__ Kg,
                                                       const __hip_bfloat16* __restrict__ Vtg,
                                                       __hip_bfloat16* __restrict__ Og) {
  __shared__ alignas(16) char smem[32768];
  float* xch = (float*)smem;  // slot stride 1280 f32: 1024 o + 256 ol
  const int tid = threadIdx.x;
  const int lane = tid & 63, w = tid >> 6;
  const int lr = lane & 15, lq = lane >> 4;
  const int qp = w >> 1;
  const int kvh = w & 1;
  const int hb = blockIdx.x, qt = blockIdx.y;
  const int h = hb >> 2, b = hb & 3;
  const size_t bh = (size_t)b * 16 + h;
  const short* Qbase = (const short*)Qg + (bh * 2048 + (size_t)qt * 64) * 64;
  const short* Kbh = (const short*)Kg + bh * 2048 * 64;
  const short* Vbh = (const short*)Vtg + bh * 64 * 2048;

  const int rbase = (lr >> 2) * 8 + (lr & 3);
  const int gk = lr & 7;

  s16x8 qb[2][2];
#pragma unroll
  for (int ntl = 0; ntl < 2; ntl++)
#pragma unroll
    for (int ks = 0; ks < 2; ks++)
      qb[ntl][ks] =
          *(const s16x8*)(Qbase + ((qp * 2 + ntl) * 16 + lr) * 64 + ks * 32 + lq * 8);

  s16x8 vones;
#pragma unroll
  for (int e = 0; e < 8; e++) vones[e] = (short)0x3F80;

  const f32x4 fz = {0.f, 0.f, 0.f, 0.f};
  f32x4 o[2][4];
  f32x4 ol[2];
#pragma unroll
  for (int i = 0; i < 2; i++) {
    ol[i] = fz;
#pragma unroll
    for (int j = 0; j < 4; j++) o[i][j] = fz;
  }

  auto stage = [&](int sel, int kb) {
    char* Kl = smem + sel * 16384;
    char* Vl = Kl + 8192;
    const short* Ksrc = Kbh + kb * 64 * 64;
#pragma unroll
    for (int r = 0; r < 2; r++) {
      int c = r * 256 + tid;
      int row = c >> 3, ck = c & 7;
      int g = (row & 3) | (((row >> 3) & 1) << 2);
      async_load16(Ksrc + row * 64 + (ck ^ g) * 8, Kl + (r * 256 + (tid & 0xC0)) * 16);
    }
#pragma unroll
    for (int r = 0; r < 2; r++) {
      int c = r * 256 + tid;
      int row = c >> 3, ck = c & 7;
      async_load16(Vbh + (size_t)row * 2048 + kb * 64 + ((ck ^ (row & 7))) * 8,
                   Vl + (r * 256 + (tid & 0xC0)) * 16);
    }
  };

  stage(0, 0);
  __syncthreads();

  for (int kb = 0; kb < 32; kb++) {
    const int cur = kb & 1;
    if (kb + 1 < 32) stage(cur ^ 1, kb + 1);

    const short* Kp = (const short*)(smem + cur * 16384);
    const short* Vp = (const short*)(smem + cur * 16384 + 8192);

    union { i32x4 i; s16x8 s; } pa[2];
#pragma unroll
    for (int mt = 0; mt < 2; mt++) {
      const int kvrow = kvh * 32 + mt * 4 + rbase;
      s16x8 kf0 = *(const s16x8*)(Kp + kvrow * 64 + (((0 * 4 + lq) ^ gk)) * 8);
      s16x8 kf1 = *(const s16x8*)(Kp + kvrow * 64 + (((1 * 4 + lq) ^ gk)) * 8);
#pragma unroll
      for (int ntl = 0; ntl < 2; ntl++) {
        f32x4 st = fz;
        st = __builtin_amdgcn_mfma_f32_16x16x32_bf16(kf0, qb[ntl][0], st, 0, 0, 0);
        st = __builtin_amdgcn_mfma_f32_16x16x32_bf16(kf1, qb[ntl][1], st, 0, 0, 0);
        float e0 = __builtin_amdgcn_exp2f(st[0]);
        float e1 = __builtin_amdgcn_exp2f(st[1]);
        float e2 = __builtin_amdgcn_exp2f(st[2]);
        float e3 = __builtin_amdgcn_exp2f(st[3]);
        pa[ntl].i[mt * 2 + 0] = (int)pack_bf16x2(e0, e1);
        pa[ntl].i[mt * 2 + 1] = (int)pack_bf16x2(e2, e3);
      }
    }
    __builtin_amdgcn_s_setprio(1);
#pragma unroll
    for (int ntl = 0; ntl < 2; ntl++)
      ol[ntl] = __builtin_amdgcn_mfma_f32_16x16x32_bf16(pa[ntl].s, vones, ol[ntl], 0, 0, 0);
#pragma unroll
    for (int ndh = 0; ndh < 4; ndh++) {
      int vrow = ndh * 16 + lr;
      s16x8 vb = *(const s16x8*)(Vp + vrow * 64 + (((kvh * 4 + lq) ^ (vrow & 7))) * 8);
#pragma unroll
      for (int ntl = 0; ntl < 2; ntl++)
        o[ntl][ndh] =
            __builtin_amdgcn_mfma_f32_16x16x32_bf16(pa[ntl].s, vb, o[ntl][ndh], 0, 0, 0);
    }
    __builtin_amdgcn_s_setprio(0);

    __syncthreads();
  }

  float* slot = xch + w * 1280;
  if (kvh == 0) {
#pragma unroll
    for (int ndh = 0; ndh < 4; ndh++)
      *(f32x4*)(slot + ndh * 256 + lane * 4) = o[1][ndh];
    *(f32x4*)(slot + 1024 + lane * 4) = ol[1];
  } else {
#pragma unroll
    for (int ndh = 0; ndh < 4; ndh++)
      *(f32x4*)(slot + ndh * 256 + lane * 4) = o[0][ndh];
    *(f32x4*)(slot + 1024 + lane * 4) = ol[0];
  }
  __syncthreads();
  const float* ps = xch + (w ^ 1) * 1280;
  if (kvh == 0) {
#pragma unroll
    for (int ndh = 0; ndh < 4; ndh++)
      o[0][ndh] += *(const f32x4*)(ps + ndh * 256 + lane * 4);
    f32x4 lt = ol[0] + *(const f32x4*)(ps + 1024 + lane * 4);
#pragma unroll
    for (int r = 0; r < 4; r++) {
      float inv = __builtin_amdgcn_rcpf(lt[r]);
      int rowg = qt * 64 + w * 16 + lq * 4 + r;
#pragma unroll
      for (int ndh = 0; ndh < 4; ndh++)
        Og[((size_t)b * 2048 + rowg) * 1024 + h * 64 + ndh * 16 + lr] =
            __float2bfloat16(o[0][ndh][r] * inv);
    }
  } else {
#pragma unroll
    for (int ndh = 0; ndh < 4; ndh++)
      o[1][ndh] += *(const f32x4*)(ps + ndh * 256 + lane * 4);
    f32x4 lt = ol[1] + *(const f32x4*)(ps + 1024 + lane * 4);
#pragma unroll
    for (int r = 0; r < 4; r++) {
      float inv = __builtin_amdgcn_rcpf(lt[r]);
      int rowg = qt * 64 + w * 16 + lq * 4 + r;
#pragma unroll
      for (int ndh = 0; ndh < 4; ndh++)
        Og[((size_t)b * 2048 + rowg) * 1024 + h * 64 + ndh * 16 + lr] =
            __float2bfloat16(o[1][ndh][r] * inv);
    }
  }
}

// ---------------- LayerNorm over last dim (1024) ----------------
__global__ __launch_bounds__(256) void ln_kernel(const float* __restrict__ tmp,
                                                 const float* __restrict__ gamma,
                                                 const float* __restrict__ beta,
                                                 float* __restrict__ out) {
  const int row = blockIdx.x, tid = threadIdx.x;
  const int lane = tid & 63, w = tid >> 6;
  const float* rp = tmp + (size_t)row * 1024;
  float4 v = ((const float4*)rp)[tid];
  float s = v.x + v.y + v.z + v.w;
  float ss = v.x * v.x + v.y * v.y + v.z * v.z + v.w * v.w;
#pragma unroll
  for (int off = 32; off >= 1; off >>= 1) {
    s += __shfl_xor(s, off);
    ss += __shfl_xor(ss, off);
  }
  __shared__ float red[8];
  if (lane == 0) {
    red[w] = s;
    red[4 + w] = ss;
  }
  __syncthreads();
  s = red[0] + red[1] + red[2] + red[3];
  ss = red[4] + red[5] + red[6] + red[7];
  const float mu = s * (1.0f / 1024.0f);
  const float var = ss * (1.0f / 1024.0f) - mu * mu;
  const float rstd = rsqrtf(var + 1e-5f);
  float4 g = ((const float4*)gamma)[tid];
  float4 be = ((const float4*)beta)[tid];
  float4 ov;
  ov.x = (v.x - mu) * rstd * g.x + be.x;
  ov.y = (v.y - mu) * rstd * g.y + be.y;
  ov.z = (v.z - mu) * rstd * g.z + be.z;
  ov.w = (v.w - mu) * rstd * g.w + be.w;
  ((float4*)(out + (size_t)row * 1024))[tid] = ov;
}

extern "C" void kernel_launch(void* const* d_in, const int* in_sizes, int n_in,
                              void* d_out, int out_size, void* d_ws, size_t ws_size,
                              hipStream_t stream) {
  (void)in_sizes; (void)n_in; (void)out_size; (void)ws_size;
  const float* x = (const float*)d_in[0];
  const float* Wq = (const float*)d_in[1];
  const float* Wk = (const float*)d_in[2];
  const float* Wv = (const float*)d_in[3];
  const float* Wo = (const float*)d_in[4];
  const float* bo = (const float*)d_in[5];
  const float* gamma = (const float*)d_in[6];
  const float* beta = (const float*)d_in[7];
  float* out = (float*)d_out;
  char* ws = (char*)d_ws;

  // workspace layout (bytes)
  __hip_bfloat16* xb = (__hip_bfloat16*)(ws + 0);          // 16 MB  [8192][1024]
  __hip_bfloat16* wqkvT = (__hip_bfloat16*)(ws + 16777216);// 6 MB   [3072][1024] (Wq x 0.125*log2e)
  __hip_bfloat16* woT = (__hip_bfloat16*)(ws + 23068672);  // 2 MB
  __hip_bfloat16* Q = (__hip_bfloat16*)(ws + 25165824);    // 16 MB [B,H,S,64]
  __hip_bfloat16* Kt = (__hip_bfloat16*)(ws + 41943040);   // 16 MB [B,H,S,64]
  __hip_bfloat16* Vt = (__hip_bfloat16*)(ws + 58720256);   // 16 MB [B,H,64,S]
  __hip_bfloat16* cc = (__hip_bfloat16*)(ws + 75497472);   // 16 MB [B,S,1024]
  float* tmp = (float*)(ws + 25165824);  // 32 MB fp32, aliases dead Q+Kt (stream-ordered)

  cast_x_kernel<<<8192, 256, 0, stream>>>(x, xb, 2097152);
  // Q scale folds 1/sqrt(64) and log2(e) so flash can use raw v_exp_f32 (exp2)
  qkv_transpose_kernel<<<dim3(16, 1, 48), 256, 0, stream>>>(Wq, Wk, Wv, wqkvT,
                                                            0.125f * 1.44269504088896f);
  transpose_cast_kernel<<<dim3(16, 16, 1), 256, 0, stream>>>(Wo, woT, 1024, 1024, 1.0f);

  // fused QKV projection: Bt = [wqT ; wkT ; wvT] (3072 rows, contiguous)
  gemm256<0><<<dim3(24, 32), 512, 0, stream>>>(xb, wqkvT, Q, Kt, Vt, nullptr, nullptr,
                                               8192, 3072, 1024);

  flash_kernel<<<dim3(64, 32), 256, 0, stream>>>(Q, Kt, Vt, cc);

  // output projection + bias + residual (fp32 tmp), deep-pipe structure (R17)
  gemm256<2><<<dim3(8, 32), 512, 0, stream>>>(cc, woT, tmp, nullptr, nullptr, bo, x,
                                              8192, 1024, 1024);
  ln_kernel<<<8192, 256, 0, stream>>>(tmp, gamma, beta, out);
}